// Round 5
// baseline (116.298 us; speedup 1.0000x reference)
//
#include <hip/hip_runtime.h>
#include <hip/hip_bf16.h>
#include <math.h>

#define N_ROWS 8192
#define DIM    512           // fp8 row = 512 B
#define BM     128
#define BKB    64            // K-slab bytes per iter (64 fp8 elems = 4 ksteps of K16)
#define NITER  (DIM / BKB)   // 8
#define NB     (N_ROWS / BM) // 64

typedef float floatx16 __attribute__((ext_vector_type(16)));
typedef long  longx2   __attribute__((ext_vector_type(2)));

// ---------------- async global->LDS, 16B per lane ----------------
__device__ __forceinline__ void load16_to_lds(const void* g, void* l) {
    __builtin_amdgcn_global_load_lds(
        (const __attribute__((address_space(1))) unsigned int*)g,
        (__attribute__((address_space(3))) unsigned int*)l,
        16, 0, 0);
}

// ------------- Kernel 1: L2-normalize fp32 -> fp8 e4m3 (x16), PERMUTED rows -
// Row byte k stored at pi(k) = 32*(k>>5) + 16*((k>>3)&1) + 8*((k>>4)&1) + (k&7)
// so that a 16B chunk holds {kstep 2s2, kstep 2s2+1} halves for one k-half h:
// b128 frag reads then serve TWO 32x32x16 MFMA ksteps each.
__global__ __launch_bounds__(128) void normalize_kernel(
    const float* __restrict__ emb, unsigned char* __restrict__ out,
    float* __restrict__ loss_out)
{
    const int row = blockIdx.x;
    const int t   = threadIdx.x;
    if (row == 0 && t == 0) loss_out[0] = 0.0f;

    const float4* rp = (const float4*)(emb + (size_t)row * DIM);
    float4 v = rp[t];
    float ss = v.x*v.x + v.y*v.y + v.z*v.z + v.w*v.w;

    #pragma unroll
    for (int off = 32; off > 0; off >>= 1) ss += __shfl_down(ss, off);

    __shared__ float sred[2];
    if ((t & 63) == 0) sred[t >> 6] = ss;
    __syncthreads();
    const float tot = sred[0] + sred[1];
    const float rs  = 16.0f / fmaxf(sqrtf(tot), 1e-12f);   // normalize * 16

    int pk = 0;
    pk = __builtin_amdgcn_cvt_pk_fp8_f32(v.x * rs, v.y * rs, pk, false);
    pk = __builtin_amdgcn_cvt_pk_fp8_f32(v.z * rs, v.w * rs, pk, true);

    const int k0  = 4 * t;                 // 4 contiguous bytes, same (s2,o,h)
    const int pos = 32*(k0 >> 5) + 16*((k0 >> 3) & 1) + 8*((k0 >> 4) & 1) + (k0 & 7);
    *(int*)(out + (size_t)row * DIM + pos) = pk;
}

// ------------- Kernel 2: fused fp8 E*E^T + contrastive loss ------------------
// 128x128 tile, 4 waves 2x2, each wave 64x64 as 2x2 of 32x32x16 fp8 MFMAs.
// LDS: double-buffered 128 x 64B slabs (32 KB total -> ~4 blocks/CU).
// 16B chunk c of row r stored at slot c ^ ((r>>1)&3): row stride 64 B flips
// bank-halves with row parity, XOR spreads within halves -> b128 frag reads
// hit every bank exactly 2x per 16-lane phase (free; round-2-verified shape).
__global__ __launch_bounds__(256) void gemmloss_kernel(
    const unsigned char* __restrict__ E, const int* __restrict__ labels,
    float* __restrict__ out)
{
    __shared__ __align__(16) unsigned char As[2][BM * BKB];  // 2 x 8 KB
    __shared__ __align__(16) unsigned char Bs[2][BM * BKB];  // 2 x 8 KB

    // ---- decode triangular block id (br <= bc) ----
    const int bid = blockIdx.x;
    int br = (int)((2.0f * NB + 1.0f -
                    sqrtf((float)((2*NB+1)*(2*NB+1) - 8*bid))) * 0.5f);
    #define TRI_START(r) ((r)*NB - ((r)*((r)-1))/2)
    while (br > 0 && TRI_START(br) > bid) --br;
    while (TRI_START(br + 1) <= bid) ++br;
    const int bc = br + (bid - TRI_START(br));
    #undef TRI_START

    const int row0 = br * BM;
    const int col0 = bc * BM;

    const int t    = threadIdx.x;
    const int wave = t >> 6;
    const int lane = t & 63;
    const int wr   = wave >> 1;   // 0..1
    const int wc   = wave & 1;    // 0..1
    const int l32  = lane & 31;   // MFMA row/col within 32
    const int h    = lane >> 5;   // k-half select

    // ---- staging: wave w stages rows [32w,32w+32) of A and B, 2 DMAs each ----
    // DMA: 16 rows x 4 chunks; lane -> row lane>>2, LDS slot lane&3,
    // global chunk g = (lane&3) ^ ((lane>>3)&3)  [slot(r,g)=g^((r>>1)&3)]
    const int sg   = (lane & 3) ^ ((lane >> 3) & 3);
    const int srow = lane >> 2;                       // 0..15
    const unsigned char* gA0 =
        E + (size_t)(row0 + 32*wave + srow) * DIM + sg * 16;
    const unsigned char* gB0 =
        E + (size_t)(col0 + 32*wave + srow) * DIM + sg * 16;
    unsigned char* lA = &As[0][0] + (32 * wave) * BKB;   // +8192 for buf 1
    unsigned char* lB = &Bs[0][0] + (32 * wave) * BKB;

    // ---- fragment read offsets ----
    // row r = wr*64 + mi*32 + l32 ; chunk c = 2*p_loc + h ;
    // addr = r*64 + ((c) ^ ((r>>1)&3))*16 ; (r>>1)&3 == (l32>>1)&3
    const int xr   = (l32 >> 1) & 3;
    const int offP0 = ((2*0 + h) ^ xr) * 16;
    const int offP1 = ((2*1 + h) ^ xr) * 16;
    const int rA = (wr*64 + l32) * BKB;   // + mi*32*BKB
    const int rB = (wc*64 + l32) * BKB;   // + ni*32*BKB

    floatx16 acc00 = {}, acc01 = {}, acc10 = {}, acc11 = {};

    // ---- prologue: slab 0 into buffer 0 ----
    load16_to_lds(gA0,                     lA);
    load16_to_lds(gA0 + (size_t)16 * DIM,  lA + 1024);
    load16_to_lds(gB0,                     lB);
    load16_to_lds(gB0 + (size_t)16 * DIM,  lB + 1024);
    __syncthreads();

    for (int it = 0; it < NITER; ++it) {
        const int b = it & 1;
        if (it + 1 < NITER) {
            const int nb = b ^ 1;
            const unsigned char* gA = gA0 + (size_t)(it + 1) * BKB;
            const unsigned char* gB = gB0 + (size_t)(it + 1) * BKB;
            load16_to_lds(gA,                    lA + nb*8192);
            load16_to_lds(gA + (size_t)16*DIM,   lA + nb*8192 + 1024);
            load16_to_lds(gB,                    lB + nb*8192);
            load16_to_lds(gB + (size_t)16*DIM,   lB + nb*8192 + 1024);
        }

        const unsigned char* cA = &As[b][0];
        const unsigned char* cB = &Bs[b][0];
        #pragma unroll
        for (int p = 0; p < 2; ++p) {
            const int off = p ? offP1 : offP0;
            longx2 a0 = *(const longx2*)(cA + rA +           off);
            longx2 a1 = *(const longx2*)(cA + rA + 32*BKB  + off);
            longx2 b0 = *(const longx2*)(cB + rB +           off);
            longx2 b1 = *(const longx2*)(cB + rB + 32*BKB  + off);
            // kstep even (.x) then odd (.y) — pi-interleaved in E8
            acc00 = __builtin_amdgcn_mfma_f32_32x32x16_fp8_fp8(a0.x, b0.x, acc00, 0, 0, 0);
            acc01 = __builtin_amdgcn_mfma_f32_32x32x16_fp8_fp8(a0.x, b1.x, acc01, 0, 0, 0);
            acc10 = __builtin_amdgcn_mfma_f32_32x32x16_fp8_fp8(a1.x, b0.x, acc10, 0, 0, 0);
            acc11 = __builtin_amdgcn_mfma_f32_32x32x16_fp8_fp8(a1.x, b1.x, acc11, 0, 0, 0);
            acc00 = __builtin_amdgcn_mfma_f32_32x32x16_fp8_fp8(a0.y, b0.y, acc00, 0, 0, 0);
            acc01 = __builtin_amdgcn_mfma_f32_32x32x16_fp8_fp8(a0.y, b1.y, acc01, 0, 0, 0);
            acc10 = __builtin_amdgcn_mfma_f32_32x32x16_fp8_fp8(a1.y, b0.y, acc10, 0, 0, 0);
            acc11 = __builtin_amdgcn_mfma_f32_32x32x16_fp8_fp8(a1.y, b1.y, acc11, 0, 0, 0);
        }
        __syncthreads();
    }

    // ---- epilogue: loss on the 64x64 wave subtile ----
    // 32x32 C/D layout: col = lane&31, row = (reg&3) + 8*(reg>>2) + 4*(lane>>5)
    // [m74/m101-verified; dtype-independent]
    float lsum = 0.0f;
    const floatx16* accs[2][2] = {{&acc00, &acc01}, {&acc10, &acc11}};
    #pragma unroll
    for (int mi = 0; mi < 2; ++mi) {
        int rl[16];
        #pragma unroll
        for (int reg = 0; reg < 16; ++reg)
            rl[reg] = labels[row0 + wr*64 + mi*32 +
                             (reg & 3) + 8*(reg >> 2) + 4*h];
        #pragma unroll
        for (int ni = 0; ni < 2; ++ni) {
            const int gj = col0 + wc*64 + ni*32 + l32;
            const int cl = labels[gj];
            const floatx16 a = *accs[mi][ni];
            #pragma unroll
            for (int reg = 0; reg < 16; ++reg) {
                const int gi = row0 + wr*64 + mi*32 +
                               (reg & 3) + 8*(reg >> 2) + 4*h;
                const float s = a[reg] * (1.0f / 256.0f);   // undo 16x16
                if (gi != gj) {
                    if (rl[reg] == cl) {
                        const float u = 1.0f - s;
                        lsum += u * u;
                    } else {
                        const float u = s - 0.5f;
                        if (u > 0.0f) lsum += u * u;
                    }
                }
            }
        }
    }

    lsum *= (br == bc) ? 1.0f : 2.0f;   // off-diagonal blocks count twice

    #pragma unroll
    for (int off = 32; off > 0; off >>= 1) lsum += __shfl_down(lsum, off);

    float* red = (float*)&As[0][0];
    if (lane == 0) red[wave] = lsum;
    __syncthreads();
    if (t == 0) {
        const float tot = red[0] + red[1] + red[2] + red[3];
        atomicAdd(out, tot * (1.0f / 67100672.0f));  // N*(N-1)
    }
}

// ---------------- launch ----------------
extern "C" void kernel_launch(void* const* d_in, const int* in_sizes, int n_in,
                              void* d_out, int out_size, void* d_ws, size_t ws_size,
                              hipStream_t stream)
{
    (void)in_sizes; (void)n_in; (void)out_size; (void)ws_size;

    const float* emb    = (const float*)d_in[0];
    const int*   labels = (const int*)d_in[1];
    float*       out    = (float*)d_out;
    unsigned char* E8   = (unsigned char*)d_ws;   // 4 MB fp8, pi-permuted rows

    normalize_kernel<<<N_ROWS, 128, 0, stream>>>(emb, E8, out);

    const int nblocks = NB * (NB + 1) / 2;   // 2080
    gemmloss_kernel<<<nblocks, 256, 0, stream>>>(E8, labels, out);
}

// Round 6
// 104.606 us; speedup vs baseline: 1.1118x; 1.1118x over previous
//
#include <hip/hip_runtime.h>
#include <hip/hip_bf16.h>
#include <math.h>

#define N_ROWS 8192
#define DIM    512           // fp8 row = 512 B
#define BM     128
#define BKB    64            // K-slab bytes per iter (64 fp8 elems = 4 ksteps of K16)
#define NITER  (DIM / BKB)   // 8
#define NB     (N_ROWS / BM) // 64
#define NBLOCKS (NB * (NB + 1) / 2)   // 2080

typedef float floatx16 __attribute__((ext_vector_type(16)));
typedef long  longx2   __attribute__((ext_vector_type(2)));

// ---------------- async global->LDS, 16B per lane ----------------
__device__ __forceinline__ void load16_to_lds(const void* g, void* l) {
    __builtin_amdgcn_global_load_lds(
        (const __attribute__((address_space(1))) unsigned int*)g,
        (__attribute__((address_space(3))) unsigned int*)l,
        16, 0, 0);
}

// ------------- Kernel 1: L2-normalize fp32 -> fp8 e4m3 (x16), PERMUTED rows -
// Row byte k stored at pi(k) = 32*(k>>5) + 16*((k>>3)&1) + 8*((k>>4)&1) + (k&7)
__global__ __launch_bounds__(128) void normalize_kernel(
    const float* __restrict__ emb, unsigned char* __restrict__ out,
    float* __restrict__ loss_out, int zero_out)
{
    const int row = blockIdx.x;
    const int t   = threadIdx.x;
    if (zero_out && row == 0 && t == 0) loss_out[0] = 0.0f;  // atomic-fallback only

    const float4* rp = (const float4*)(emb + (size_t)row * DIM);
    float4 v = rp[t];
    float ss = v.x*v.x + v.y*v.y + v.z*v.z + v.w*v.w;

    #pragma unroll
    for (int off = 32; off > 0; off >>= 1) ss += __shfl_down(ss, off);

    __shared__ float sred[2];
    if ((t & 63) == 0) sred[t >> 6] = ss;
    __syncthreads();
    const float tot = sred[0] + sred[1];
    const float rs  = 16.0f / fmaxf(sqrtf(tot), 1e-12f);   // normalize * 16

    int pk = 0;
    pk = __builtin_amdgcn_cvt_pk_fp8_f32(v.x * rs, v.y * rs, pk, false);
    pk = __builtin_amdgcn_cvt_pk_fp8_f32(v.z * rs, v.w * rs, pk, true);

    const int k0  = 4 * t;
    const int pos = 32*(k0 >> 5) + 16*((k0 >> 3) & 1) + 8*((k0 >> 4) & 1) + (k0 & 7);
    *(int*)(out + (size_t)row * DIM + pos) = pk;
}

// ------------- Kernel 2: fused fp8 E*E^T + contrastive loss ------------------
// 128x128 tile, 4 waves 2x2, each wave 64x64 as 2x2 of 32x32x16 fp8 MFMAs.
// Partial loss per block -> partials[bid] (distinct addresses, no contention).
__global__ __launch_bounds__(256) void gemmloss_kernel(
    const unsigned char* __restrict__ E, const int* __restrict__ labels,
    float* __restrict__ partials, float* __restrict__ out, int use_partials)
{
    __shared__ __align__(16) unsigned char As[2][BM * BKB];  // 2 x 8 KB
    __shared__ __align__(16) unsigned char Bs[2][BM * BKB];  // 2 x 8 KB

    // ---- decode triangular block id (br <= bc) ----
    const int bid = blockIdx.x;
    int br = (int)((2.0f * NB + 1.0f -
                    sqrtf((float)((2*NB+1)*(2*NB+1) - 8*bid))) * 0.5f);
    #define TRI_START(r) ((r)*NB - ((r)*((r)-1))/2)
    while (br > 0 && TRI_START(br) > bid) --br;
    while (TRI_START(br + 1) <= bid) ++br;
    const int bc = br + (bid - TRI_START(br));
    #undef TRI_START

    const int row0 = br * BM;
    const int col0 = bc * BM;

    const int t    = threadIdx.x;
    const int wave = t >> 6;
    const int lane = t & 63;
    const int wr   = wave >> 1;   // 0..1
    const int wc   = wave & 1;    // 0..1
    const int l32  = lane & 31;
    const int h    = lane >> 5;   // k-half select

    // ---- staging: wave w stages rows [32w,32w+32) of A and B, 2 DMAs each ----
    const int sg   = (lane & 3) ^ ((lane >> 3) & 3);
    const int srow = lane >> 2;                       // 0..15
    const unsigned char* gA0 =
        E + (size_t)(row0 + 32*wave + srow) * DIM + sg * 16;
    const unsigned char* gB0 =
        E + (size_t)(col0 + 32*wave + srow) * DIM + sg * 16;
    unsigned char* lA = &As[0][0] + (32 * wave) * BKB;   // +8192 for buf 1
    unsigned char* lB = &Bs[0][0] + (32 * wave) * BKB;

    // ---- fragment read offsets ----
    const int xr   = (l32 >> 1) & 3;
    const int offP0 = ((2*0 + h) ^ xr) * 16;
    const int offP1 = ((2*1 + h) ^ xr) * 16;
    const int rA = (wr*64 + l32) * BKB;   // + mi*32*BKB
    const int rB = (wc*64 + l32) * BKB;   // + ni*32*BKB

    floatx16 acc00 = {}, acc01 = {}, acc10 = {}, acc11 = {};

    // ---- prologue: slab 0 into buffer 0 ----
    load16_to_lds(gA0,                     lA);
    load16_to_lds(gA0 + (size_t)16 * DIM,  lA + 1024);
    load16_to_lds(gB0,                     lB);
    load16_to_lds(gB0 + (size_t)16 * DIM,  lB + 1024);
    __syncthreads();

    for (int it = 0; it < NITER; ++it) {
        const int b = it & 1;
        if (it + 1 < NITER) {
            const int nb = b ^ 1;
            const unsigned char* gA = gA0 + (size_t)(it + 1) * BKB;
            const unsigned char* gB = gB0 + (size_t)(it + 1) * BKB;
            load16_to_lds(gA,                    lA + nb*8192);
            load16_to_lds(gA + (size_t)16*DIM,   lA + nb*8192 + 1024);
            load16_to_lds(gB,                    lB + nb*8192);
            load16_to_lds(gB + (size_t)16*DIM,   lB + nb*8192 + 1024);
        }

        const unsigned char* cA = &As[b][0];
        const unsigned char* cB = &Bs[b][0];
        #pragma unroll
        for (int p = 0; p < 2; ++p) {
            const int off = p ? offP1 : offP0;
            longx2 a0 = *(const longx2*)(cA + rA +          off);
            longx2 a1 = *(const longx2*)(cA + rA + 32*BKB + off);
            longx2 b0 = *(const longx2*)(cB + rB +          off);
            longx2 b1 = *(const longx2*)(cB + rB + 32*BKB + off);
            acc00 = __builtin_amdgcn_mfma_f32_32x32x16_fp8_fp8(a0.x, b0.x, acc00, 0, 0, 0);
            acc01 = __builtin_amdgcn_mfma_f32_32x32x16_fp8_fp8(a0.x, b1.x, acc01, 0, 0, 0);
            acc10 = __builtin_amdgcn_mfma_f32_32x32x16_fp8_fp8(a1.x, b0.x, acc10, 0, 0, 0);
            acc11 = __builtin_amdgcn_mfma_f32_32x32x16_fp8_fp8(a1.x, b1.x, acc11, 0, 0, 0);
            acc00 = __builtin_amdgcn_mfma_f32_32x32x16_fp8_fp8(a0.y, b0.y, acc00, 0, 0, 0);
            acc01 = __builtin_amdgcn_mfma_f32_32x32x16_fp8_fp8(a0.y, b1.y, acc01, 0, 0, 0);
            acc10 = __builtin_amdgcn_mfma_f32_32x32x16_fp8_fp8(a1.y, b0.y, acc10, 0, 0, 0);
            acc11 = __builtin_amdgcn_mfma_f32_32x32x16_fp8_fp8(a1.y, b1.y, acc11, 0, 0, 0);
        }
        __syncthreads();
    }

    // ---- epilogue: loss on the 64x64 wave subtile ----
    // 32x32 C/D layout: col = lane&31, row = (reg&3)+8*(reg>>2)+4*(lane>>5)
    float lsum = 0.0f;
    const floatx16* accs[2][2] = {{&acc00, &acc01}, {&acc10, &acc11}};
    #pragma unroll
    for (int mi = 0; mi < 2; ++mi) {
        int rl[16];
        #pragma unroll
        for (int reg = 0; reg < 16; ++reg)
            rl[reg] = labels[row0 + wr*64 + mi*32 +
                             (reg & 3) + 8*(reg >> 2) + 4*h];
        #pragma unroll
        for (int ni = 0; ni < 2; ++ni) {
            const int gj = col0 + wc*64 + ni*32 + l32;
            const int cl = labels[gj];
            const floatx16 a = *accs[mi][ni];
            #pragma unroll
            for (int reg = 0; reg < 16; ++reg) {
                const int gi = row0 + wr*64 + mi*32 +
                               (reg & 3) + 8*(reg >> 2) + 4*h;
                const float s = a[reg] * (1.0f / 256.0f);   // undo 16x16
                if (gi != gj) {
                    if (rl[reg] == cl) {
                        const float u = 1.0f - s;
                        lsum += u * u;
                    } else {
                        const float u = s - 0.5f;
                        if (u > 0.0f) lsum += u * u;
                    }
                }
            }
        }
    }

    lsum *= (br == bc) ? 1.0f : 2.0f;   // off-diagonal blocks count twice

    #pragma unroll
    for (int off = 32; off > 0; off >>= 1) lsum += __shfl_down(lsum, off);

    float* red = (float*)&As[0][0];
    if (lane == 0) red[wave] = lsum;
    __syncthreads();
    if (t == 0) {
        const float tot = red[0] + red[1] + red[2] + red[3];
        if (use_partials) partials[bid] = tot;                       // no contention
        else atomicAdd(out, tot * (1.0f / 67100672.0f));             // fallback
    }
}

// ------------- Kernel 3: sum 2080 partials -> d_out --------------------------
__global__ __launch_bounds__(256) void reduce_kernel(
    const float* __restrict__ partials, float* __restrict__ out)
{
    const int t = threadIdx.x;
    float s = 0.0f;
    for (int i = t; i < NBLOCKS; i += 256) s += partials[i];
    #pragma unroll
    for (int off = 32; off > 0; off >>= 1) s += __shfl_down(s, off);
    __shared__ float r[4];
    if ((t & 63) == 0) r[t >> 6] = s;
    __syncthreads();
    if (t == 0)
        out[0] = (r[0] + r[1] + r[2] + r[3]) * (1.0f / 67100672.0f); // N*(N-1)
}

// ---------------- launch ----------------
extern "C" void kernel_launch(void* const* d_in, const int* in_sizes, int n_in,
                              void* d_out, int out_size, void* d_ws, size_t ws_size,
                              hipStream_t stream)
{
    (void)in_sizes; (void)n_in; (void)out_size;

    const float* emb    = (const float*)d_in[0];
    const int*   labels = (const int*)d_in[1];
    float*       out    = (float*)d_out;
    unsigned char* E8   = (unsigned char*)d_ws;   // 4 MB fp8, pi-permuted rows

    const size_t e8_bytes = (size_t)N_ROWS * DIM;
    const int use_partials = (ws_size >= e8_bytes + NBLOCKS * sizeof(float)) ? 1 : 0;
    float* partials = (float*)((unsigned char*)d_ws + e8_bytes);

    normalize_kernel<<<N_ROWS, 128, 0, stream>>>(emb, E8, out, !use_partials);
    gemmloss_kernel<<<NBLOCKS, 256, 0, stream>>>(E8, labels, partials, out, use_partials);
    if (use_partials)
        reduce_kernel<<<1, 256, 0, stream>>>(partials, out);
}